// Round 30
// baseline (40.508 us; speedup 1.0000x reference)
//
#include <hip/hip_runtime.h>

// GaussianAntecedent: out[n,r] = mem[n,r] / (sum_r mem[n,r] + 1e-8)
// mem = exp2( -sum_d clamp(q*(x-c), +-K)^2 ),  K = sqrt(-log2(1e-8))
//   q = sqrt(0.5*log2 e)/(sigma+eps)
//
// R29 post-mortem: all scheduling attacks neutral; the ~16us stall
// matches the LDS-pipe service model (800k uniform ds_read_b128 x 12cy
// / 256 CU = 15.6us/CU). R19's s_load escape failed for removable
// reasons: in-loop ds_writes entangled lgkmcnt. R30 = rule loop with
// ZERO LDS and ZERO VMEM ops:
//  - constants: wave-uniform s_loads from 16KB global table (K$, scalar
//    pipe); lgkmcnt in the loop counts ONLY s_loads now
//  - mem -> REGISTERS (mema/memb[16], static idx); memH ds_writes moved
//    after the loop
//  - inner: z=x-c(1s); y=z*q(1s); med3; fma  (4 ops/elem, +1 = the
//    price of the test)
//  - kept: R28 coalesced X staging, bf16 memH (absmax 550x margin),
//    contiguous epilogue. launch_bounds(256,3).

constexpr int DDIM = 32;
constexpr int RR   = 64;
constexpr int ROWS = 128;   // rows per block (2 per lane)
constexpr int PP   = 5;     // partials pitch (floats)
constexpr int XP   = 33;    // X stage pitch (floats)
constexpr int MPH  = 130;   // mem tile pitch (ushorts); word-pitch 65 (odd)

__device__ inline float fast_exp2(float x) {
#if __has_builtin(__builtin_amdgcn_exp2f)
    return __builtin_amdgcn_exp2f(x);
#else
    return exp2f(x);
#endif
}

__device__ inline unsigned short f2bf(float x) {
    return (unsigned short)((__float_as_uint(x) + 0x8000u) >> 16);
}
__device__ inline float bf2f(unsigned short h) {
    return __uint_as_float(((unsigned int)h) << 16);
}

// ---- setup: per-rule table [ c[0..31] | q[0..31] ] (64 floats/rule) ----
__global__ void gauss_setup_kernel(const float* __restrict__ centers,
                                   const float* __restrict__ sigma,
                                   float* __restrict__ ws) {
    const float SQK = 0.84932180028801907f;   // sqrt(0.5 * log2(e))
    int idx = blockIdx.x * blockDim.x + threadIdx.x;
    if (idx < RR * DDIM) {
        int r = idx >> 5, d = idx & 31;
        ws[r * 64 + d]        = centers[r * DDIM + d];
        ws[r * 64 + DDIM + d] = SQK * __builtin_amdgcn_rcpf(
                                    sigma[r * DDIM + d] + 1e-8f);
    }
}

__global__ __launch_bounds__(256, 3) void gauss_main(
    const float* __restrict__ X,
    const float* __restrict__ tab,    // d_ws: 64 rules x [c[32]|q[32]]
    float* __restrict__ out, int N)
{
    __shared__ float bufL[ROWS * XP];      // 16.9 KB: xsL then memH (alias)
    __shared__ float partL[ROWS * PP];     // 2.56 KB [row][wave]
    __shared__ float rsL[ROWS];            // 0.5 KB  rcp(S) per row
    float* xsL = bufL;                             // [128][33] staged X
    unsigned short* memH = (unsigned short*)bufL;  // [64][130] bf16 mem

    const int tid  = threadIdx.x;
    const int lane = tid & 63;
    // wave index forced uniform so constant reads take the scalar path
    const int w    = __builtin_amdgcn_readfirstlane(tid >> 6);
    const int n0   = blockIdx.x * ROWS;

    // ---- coalesced X loads: 4 float4/thread, linear over the 16KB tile ----
    float4 xg[4];
    #pragma unroll
    for (int k = 0; k < 4; ++k) {
        const int f   = k * 256 + tid;       // float4 index 0..1023
        const int row = f >> 3;              // 0..127
        const int col = (f & 7) * 4;         // 0..28
        int rsrc = n0 + row; if (rsrc >= N) rsrc = N - 1;
        xg[k] = *reinterpret_cast<const float4*>(X + (size_t)rsrc * DDIM + col);
    }
    #pragma unroll
    for (int k = 0; k < 4; ++k) {
        const int f   = k * 256 + tid;
        const int row = f >> 3;
        const int col = (f & 7) * 4;
        xsL[row * XP + col + 0] = xg[k].x;
        xsL[row * XP + col + 1] = xg[k].y;
        xsL[row * XP + col + 2] = xg[k].z;
        xsL[row * XP + col + 3] = xg[k].w;
    }
    __syncthreads();   // bar1: xsL ready

    // ---- own 2 rows -> registers (scalar floats for the 1-SGPR form) ----
    float xa[DDIM], xb[DDIM];
    #pragma unroll
    for (int d = 0; d < DDIM; ++d) {
        xa[d] = xsL[lane * XP + d];
        xb[d] = xsL[(64 + lane) * XP + d];
    }
    __syncthreads();   // bar2: xsL dead; memH may be written later

    const float K = 5.1551357f;   // sqrt(26.575424759098897) = sqrt(-log2 1e-8)
    const int rbase = w * 16;
    float Sa = 0.f, Sb = 0.f;
    float mema[16], memb[16];     // static indexing only (fully unrolled)

    // ---- 16 rules; constants via wave-uniform s_loads; NO LDS/VMEM ----
    #pragma unroll
    for (int rr = 0; rr < 16; ++rr) {
        const int r = rbase + rr;                     // wave-uniform
        const float* __restrict__ tr = tab + r * 64;  // -> s_load_dwordx16

        float A0 = 0.f, A1 = 0.f, A2 = 0.f, A3 = 0.f;
        float B0 = 0.f, B1 = 0.f, B2 = 0.f, B3 = 0.f;
        #pragma unroll
        for (int d = 0; d < DDIM; d += 4) {
            float c0 = tr[d+0], c1 = tr[d+1], c2 = tr[d+2], c3 = tr[d+3];
            float q0 = tr[DDIM+d+0], q1 = tr[DDIM+d+1];
            float q2 = tr[DDIM+d+2], q3 = tr[DDIM+d+3];
            float ya0 = (xa[d+0] - c0) * q0;     // each op: <=1 SGPR
            float ya1 = (xa[d+1] - c1) * q1;
            float ya2 = (xa[d+2] - c2) * q2;
            float ya3 = (xa[d+3] - c3) * q3;
            float yb0 = (xb[d+0] - c0) * q0;
            float yb1 = (xb[d+1] - c1) * q1;
            float yb2 = (xb[d+2] - c2) * q2;
            float yb3 = (xb[d+3] - c3) * q3;
            ya0 = fminf(fmaxf(ya0, -K), K); ya1 = fminf(fmaxf(ya1, -K), K);
            ya2 = fminf(fmaxf(ya2, -K), K); ya3 = fminf(fmaxf(ya3, -K), K);
            yb0 = fminf(fmaxf(yb0, -K), K); yb1 = fminf(fmaxf(yb1, -K), K);
            yb2 = fminf(fmaxf(yb2, -K), K); yb3 = fminf(fmaxf(yb3, -K), K);
            A0 = fmaf(ya0, -ya0, A0); A1 = fmaf(ya1, -ya1, A1);
            A2 = fmaf(ya2, -ya2, A2); A3 = fmaf(ya3, -ya3, A3);
            B0 = fmaf(yb0, -yb0, B0); B1 = fmaf(yb1, -yb1, B1);
            B2 = fmaf(yb2, -yb2, B2); B3 = fmaf(yb3, -yb3, B3);
        }
        float ma = fast_exp2((A0 + A1) + (A2 + A3));
        float mb = fast_exp2((B0 + B1) + (B2 + B3));
        mema[rr] = ma;
        memb[rr] = mb;
        Sa += ma;
        Sb += mb;
    }

    // ---- mem tile writes, batched AFTER the loop (no lgkm entanglement) ----
    #pragma unroll
    for (int rr = 0; rr < 16; ++rr) {
        const int r = rbase + rr;
        memH[r * MPH + lane]      = f2bf(mema[rr]);
        memH[r * MPH + 64 + lane] = f2bf(memb[rr]);
    }
    partL[lane * PP + w]        = Sa;    // (5*lane+w)%32: 2-way, free
    partL[(64 + lane) * PP + w] = Sb;

    __syncthreads();   // bar3: mem tile + partials ready

    if (tid < ROWS) {
        float s = partL[tid * PP + 0] + partL[tid * PP + 1] +
                  partL[tid * PP + 2] + partL[tid * PP + 3];
        rsL[tid] = __builtin_amdgcn_rcpf(s + 1e-8f);
    }
    __syncthreads();   // bar4: rs ready

    // ---- epilogue: contiguous 4KB-per-step float4 stores ----
    const int nvalid = N - n0;   // rows in this block (128 except last)
    #pragma unroll
    for (int ch = 0; ch < 8; ++ch) {
        const int f4  = ch * 256 + tid;       // 0..2047
        const int row = f4 >> 4;              // 0..127
        const int r4  = (f4 & 15) * 4;        // rule quad base
        if (row < nvalid) {
            float rs = rsL[row];
            float4 o;
            o.x = bf2f(memH[(r4 + 0) * MPH + row]) * rs;
            o.y = bf2f(memH[(r4 + 1) * MPH + row]) * rs;
            o.z = bf2f(memH[(r4 + 2) * MPH + row]) * rs;
            o.w = bf2f(memH[(r4 + 3) * MPH + row]) * rs;
            *reinterpret_cast<float4*>(&out[(size_t)(n0 + row) * RR + r4]) = o;
        }
    }
}

extern "C" void kernel_launch(void* const* d_in, const int* in_sizes, int n_in,
                              void* d_out, int out_size, void* d_ws, size_t ws_size,
                              hipStream_t stream) {
    const float* X       = (const float*)d_in[0];
    const float* centers = (const float*)d_in[1];
    const float* sigma   = (const float*)d_in[2];
    float* out = (float*)d_out;
    float* ws  = (float*)d_ws;   // needs 64*64*4 = 16 KB

    const int N = in_sizes[0] / DDIM;  // 100000

    // 1) build per-rule c/q table (2048 elems)
    gauss_setup_kernel<<<8, 256, 0, stream>>>(centers, sigma, ws);

    // 2) main: 782 blocks x 256 threads
    const int grid = (N + ROWS - 1) / ROWS;
    gauss_main<<<grid, 256, 0, stream>>>(X, ws, out, N);
}